// Round 14
// baseline (112.646 us; speedup 1.0000x reference)
//
#include <hip/hip_runtime.h>

// R13 = R10 (best, 61.4 us) + x3 body replay in weak/strong for MEASUREMENT.
// The replay is made un-CSE-able via a runtime `dead=0` offset; weak's
// atomicMax replay is idempotent, strong scales its 3x accumulation by 1/3.
// Purpose: force the two heavy kernels above the harness's 46-us poison
// fills so their true dur/VALUBusy/FETCH/Occupancy appear in the top-5,
// and recover per-kernel shares from dur delta vs R10.
constexpr int kReps = 3;

constexpr int kN = 4, kC = 19, kH = 512, kW = 512;
constexpr int kHW = kH * kW;
constexpr int kS = 2048;      // NUM_SUPERPIXEL
constexpr int kSsm = 8192;    // NUM_SMALL
constexpr float kEps = 1e-8f;

constexpr int kNSC = kN * kS * kC;                 // need_mark domain (155,648)
constexpr int kPixBlocks = kN * kHW / 256;         // 4096 (exact)

// ---- workspace layout (bytes) ----
constexpr size_t OFF_AMAX = 0;                                   // u64[N*S*C] (value_bits<<32)|~pix
constexpr size_t SZ_AMAX  = (size_t)kN * kS * kC * 8;
constexpr size_t OFF_MULT = OFF_AMAX + SZ_AMAX;                  // u32[N*Ssm*C] multiplicity
constexpr size_t SZ_MULT  = (size_t)kN * kSsm * kC * 4;
constexpr size_t OFF_NM   = OFF_MULT + SZ_MULT;                  // u32[N*Ssm] needed-channel bits
constexpr size_t SZ_NM    = (size_t)kN * kSsm * 4;
constexpr size_t ZERO_BYTES = OFF_NM + SZ_NM;                    // zeroed region (16B-multiple)
constexpr size_t ZERO_CHUNKS = ZERO_BYTES / 16;
constexpr size_t OFF_TM   = ZERO_BYTES;                          // u32[N*S] target channel bitmask
constexpr size_t SZ_TM    = (size_t)kN * kS * 4;
constexpr size_t OFF_PL   = OFF_TM + SZ_TM;                      // f32[kPixBlocks] loss partials
constexpr size_t SZ_PL    = (size_t)kPixBlocks * 4;
constexpr size_t OFF_PN   = OFF_PL + SZ_PL;                      // i32[kPixBlocks] nv partials
constexpr size_t SZ_PN    = (size_t)kPixBlocks * 4;
constexpr size_t WS_TOTAL = OFF_PN + SZ_PN;

// Fused: zero the accumulator region + build tmask.
__global__ void init_kernel(const float* __restrict__ targets,
                            unsigned* __restrict__ tmask,
                            ulong2* __restrict__ ws) {
    size_t gid = (size_t)blockIdx.x * blockDim.x + threadIdx.x;
    if (gid < ZERO_CHUNKS) ws[gid] = ulong2{0ULL, 0ULL};
    if (gid < (size_t)kN * kS) {
        const float* t = targets + gid * (kC + 1);
        unsigned m = 0;
#pragma unroll
        for (int c = 0; c < kC; ++c)
            if (t[c] > 0.f) m |= (1u << c);
        tmask[gid] = m;
    }
}

// Weak branch (R10): per-(segment,channel) lexicographic argmax via
// fire-and-forget u64 atomicMax of (float_bits(v)<<32)|~pixel.
// MEASUREMENT: body replayed kReps times (dead=0 defeats CSE; atomicMax
// replay is idempotent).
__global__ void weak_argmax_kernel(const float* __restrict__ logits,
                                   const unsigned char* __restrict__ mask,
                                   const int* __restrict__ seg,
                                   const unsigned* __restrict__ tmask,
                                   unsigned long long* __restrict__ amax,
                                   int dead) {
    int gid = blockIdx.x * blockDim.x + threadIdx.x;
    if (!mask[gid]) return;
    int n = gid >> 18;
    int p = gid & (kHW - 1);
    int s = seg[gid];
    unsigned tm = tmask[n * kS + s];
    if (!tm) return;

    unsigned long long lowbits = (unsigned int)(~(unsigned int)p);
    unsigned long long* dst = amax + ((size_t)n * kS + s) * kC;

    for (int rep = 0; rep < kReps; ++rep) {
        const float* base =
            logits + (size_t)n * kC * kHW + p + (size_t)(rep * dead);
        float sum = 0.f;
#pragma unroll
        for (int c = 0; c < kC; ++c)
            sum += __expf(base[(size_t)c * kHW]);
        float inv = 1.f / sum;

        unsigned bits = tm;
        while (bits) {
            int c = __ffs(bits) - 1;
            bits &= bits - 1;
            float v = __expf(base[(size_t)c * kHW]) * inv;  // L1-hot reload
            unsigned long long key =
                ((unsigned long long)__float_as_uint(v) << 32) | lowbits;
            atomicMax(&dst[c], key);
        }
    }
}

// For each live (n,s,c) pair: record needed-channel bit and multiplicity.
// (R10 summation-order swap: mult lets strong emit the final loss directly.)
__global__ void need_mark_kernel(const unsigned long long* __restrict__ amax,
                                 const unsigned* __restrict__ tmask,
                                 const int* __restrict__ small_w,
                                 unsigned* __restrict__ needmask,
                                 unsigned* __restrict__ mult) {
    int gid = blockIdx.x * blockDim.x + threadIdx.x;
    if (gid >= kNSC) return;
    int n = gid / (kS * kC);
    int rem = gid - n * (kS * kC);
    int s = rem / kC;
    int c = rem - s * kC;
    if (!((tmask[n * kS + s] >> c) & 1u)) return;
    unsigned long long packed = amax[gid];
    if (packed == 0ULL) return;  // empty segment (has_pixel == false)
    unsigned pix = ~(unsigned)(packed & 0xFFFFFFFFULL);
    int sel = small_w[(size_t)n * kHW + pix];
    atomicOr(&needmask[n * kSsm + sel], 1u << c);
    atomicAdd(&mult[((size_t)n * kSsm + sel) * kC + c], 1u);
}

// Strong branch (R10): softmax + mult-weighted nll, block-reduced.
// MEASUREMENT: body replayed kReps times, result scaled by 1/kReps
// (int part divides exactly; float part ~2ulp rounding).
__global__ void strong_loss_kernel(const float* __restrict__ logits,
                                   const unsigned char* __restrict__ mask,
                                   const int* __restrict__ seg,
                                   const unsigned* __restrict__ needmask,
                                   const unsigned* __restrict__ mult,
                                   float* __restrict__ ploss,
                                   int* __restrict__ pnv,
                                   int dead) {
    __shared__ float sLoss[4];
    __shared__ int sNv[4];
    int gid = blockIdx.x * blockDim.x + threadIdx.x;  // exact grid
    float loss = 0.f;
    int nvv = 0;
    if (mask[gid]) {
        int n = gid >> 18;
        int p = gid & (kHW - 1);
        int ss = seg[gid];
        unsigned nm = needmask[n * kSsm + ss];
        if (nm) {
            const unsigned* row = mult + ((size_t)n * kSsm + ss) * kC;
            for (int rep = 0; rep < kReps; ++rep) {
                const float* base =
                    logits + (size_t)n * kC * kHW + p + (size_t)(rep * dead);
                float sum = 0.f;
#pragma unroll
                for (int c = 0; c < kC; ++c)
                    sum += __expf(base[(size_t)c * kHW]);
                float inv = 1.f / sum;

                unsigned bits = nm;
                while (bits) {
                    int c = __ffs(bits) - 1;
                    bits &= bits - 1;
                    unsigned m = row[c];                            // L2-resident
                    float v = __expf(base[(size_t)c * kHW]) * inv;  // L1-hot
                    loss += (float)m * (-__logf(v + kEps));
                    nvv += (int)m;
                }
            }
            loss *= (1.f / kReps);
            nvv /= kReps;
        }
    }
    // all threads reach here (no early returns) — block reduction
#pragma unroll
    for (int off = 32; off > 0; off >>= 1) {
        loss += __shfl_down(loss, off);
        nvv += __shfl_down(nvv, off);
    }
    int wave = threadIdx.x >> 6;
    if ((threadIdx.x & 63) == 0) {
        sLoss[wave] = loss;
        sNv[wave] = nvv;
    }
    __syncthreads();
    if (threadIdx.x == 0) {
        ploss[blockIdx.x] = sLoss[0] + sLoss[1] + sLoss[2] + sLoss[3];
        pnv[blockIdx.x]   = sNv[0] + sNv[1] + sNv[2] + sNv[3];
    }
}

// Single-block reduction of the 4096 per-block partials + final divide.
__global__ void finalize_kernel(const float* __restrict__ ploss,
                                const int* __restrict__ pnv,
                                float* __restrict__ out) {
    __shared__ float sLoss[4];
    __shared__ int sNv[4];
    float lv = 0.f;
    int nvv = 0;
    for (int i = threadIdx.x; i < kPixBlocks; i += 256) {
        lv += ploss[i];
        nvv += pnv[i];
    }
#pragma unroll
    for (int off = 32; off > 0; off >>= 1) {
        lv += __shfl_down(lv, off);
        nvv += __shfl_down(nvv, off);
    }
    int wave = threadIdx.x >> 6;
    if ((threadIdx.x & 63) == 0) {
        sLoss[wave] = lv;
        sNv[wave] = nvv;
    }
    __syncthreads();
    if (threadIdx.x == 0) {
        float tl = sLoss[0] + sLoss[1] + sLoss[2] + sLoss[3];
        int tn = sNv[0] + sNv[1] + sNv[2] + sNv[3];
        out[0] = tl / (float)(1 + tn);
    }
}

extern "C" void kernel_launch(void* const* d_in, const int* in_sizes, int n_in,
                              void* d_out, int out_size, void* d_ws, size_t ws_size,
                              hipStream_t stream) {
    const float* inputs            = (const float*)d_in[0];
    const float* inputs_weak       = (const float*)d_in[1];
    const float* targets           = (const float*)d_in[2];
    const unsigned char* spmasks      = (const unsigned char*)d_in[3];
    const unsigned char* spmasks_weak = (const unsigned char*)d_in[4];
    // d_in[5] superpixels: unused by the reference
    const int* superpixels_weak    = (const int*)d_in[6];
    const int* superpixel_smalls   = (const int*)d_in[7];
    const int* spx_smalls_weak     = (const int*)d_in[8];
    float* out = (float*)d_out;

    unsigned long long* amax = (unsigned long long*)((char*)d_ws + OFF_AMAX);
    unsigned* mult           = (unsigned*)((char*)d_ws + OFF_MULT);
    unsigned* needmask       = (unsigned*)((char*)d_ws + OFF_NM);
    unsigned* tmask          = (unsigned*)((char*)d_ws + OFF_TM);
    float* ploss             = (float*)((char*)d_ws + OFF_PL);
    int* pnv                 = (int*)((char*)d_ws + OFF_PN);

    int initThreads = (int)ZERO_CHUNKS;
    init_kernel<<<(initThreads + 255) / 256, 256, 0, stream>>>(targets, tmask,
                                                               (ulong2*)d_ws);
    weak_argmax_kernel<<<kPixBlocks, 256, 0, stream>>>(inputs_weak, spmasks_weak,
                                                       superpixels_weak, tmask,
                                                       amax, /*dead=*/0);
    need_mark_kernel<<<(kNSC + 255) / 256, 256, 0, stream>>>(amax, tmask,
                                                             spx_smalls_weak,
                                                             needmask, mult);
    strong_loss_kernel<<<kPixBlocks, 256, 0, stream>>>(inputs, spmasks,
                                                       superpixel_smalls,
                                                       needmask, mult, ploss, pnv,
                                                       /*dead=*/0);
    finalize_kernel<<<1, 256, 0, stream>>>(ploss, pnv, out);
}

// Round 15
// 62.351 us; speedup vs baseline: 1.8066x; 1.8066x over previous
//
#include <hip/hip_runtime.h>

constexpr int kN = 4, kC = 19, kH = 512, kW = 512;
constexpr int kHW = kH * kW;                       // 2^18
constexpr int kS = 2048;      // NUM_SUPERPIXEL
constexpr int kSsm = 8192;    // NUM_SMALL
constexpr float kEps = 1e-8f;

constexpr int kNSC = kN * kS * kC;                 // need_mark domain (155,648)
constexpr int kPixBlocks = kN * kHW / 256;         // 4096 (exact)

// ---- workspace layout (bytes) ----
constexpr size_t OFF_AMAX = 0;                                   // u64[N*S*C] (value_bits<<32)|~pix
constexpr size_t SZ_AMAX  = (size_t)kN * kS * kC * 8;
constexpr size_t OFF_MULT = OFF_AMAX + SZ_AMAX;                  // u32[N*Ssm*C] multiplicity
constexpr size_t SZ_MULT  = (size_t)kN * kSsm * kC * 4;
constexpr size_t OFF_NM   = OFF_MULT + SZ_MULT;                  // u32[N*Ssm] needed-channel bits
constexpr size_t SZ_NM    = (size_t)kN * kSsm * 4;
constexpr size_t ZERO_BYTES = OFF_NM + SZ_NM;                    // zeroed region (16B-multiple)
constexpr size_t ZERO_CHUNKS = ZERO_BYTES / 16;
constexpr size_t OFF_TM   = ZERO_BYTES;                          // u32[N*S] target channel bitmask
constexpr size_t SZ_TM    = (size_t)kN * kS * 4;
constexpr size_t OFF_PL   = OFF_TM + SZ_TM;                      // f32[kPixBlocks] loss partials
constexpr size_t SZ_PL    = (size_t)kPixBlocks * 4;
constexpr size_t OFF_PN   = OFF_PL + SZ_PL;                      // i32[kPixBlocks] nv partials
constexpr size_t SZ_PN    = (size_t)kPixBlocks * 4;
constexpr size_t WS_TOTAL = OFF_PN + SZ_PN;

// Fused: zero the accumulator region + build tmask.
__global__ void init_kernel(const float* __restrict__ targets,
                            unsigned* __restrict__ tmask,
                            ulong2* __restrict__ ws) {
    size_t gid = (size_t)blockIdx.x * blockDim.x + threadIdx.x;
    if (gid < ZERO_CHUNKS) ws[gid] = ulong2{0ULL, 0ULL};
    if (gid < (size_t)kN * kS) {
        const float* t = targets + gid * (kC + 1);
        unsigned m = 0;
#pragma unroll
        for (int c = 0; c < kC; ++c)
            if (t[c] > 0.f) m |= (1u << c);
        tmask[gid] = m;
    }
}

// Weak branch, R14: LDS-staged channel tile.
// R13 measurement: a WARM replay of the old per-thread loop cost 20 µs
// (VALU only 4.6) — the channel stride is 2^20 B so all 19 loads of a
// pixel alias to the SAME L1 set => every load is an L2 round trip,
// serialized at VGPR-limited MLP. Fix: block-cooperative async DMA of the
// [19][256] tile into LDS (global_load_lds: no VGPR round trip, one vmcnt
// drain), softmax reads LDS (2 lanes/bank = conflict-free). 19 KB/block
// -> 8 blocks/CU -> full 32-wave occupancy.
__global__ void weak_argmax_kernel(const float* __restrict__ logits,
                                   const unsigned char* __restrict__ mask,
                                   const int* __restrict__ seg,
                                   const unsigned* __restrict__ tmask,
                                   unsigned long long* __restrict__ amax) {
    __shared__ float sT[kC][256];
    int tid = threadIdx.x;
    int n = blockIdx.x >> 10;                 // 1024 blocks per n
    int p0 = (blockIdx.x & 1023) << 8;        // block's first pixel
    int p = p0 + tid;
    int gid = n * kHW + p;
    int wslot = (tid >> 6) << 6;              // wave's 64-pixel slot base

    // Async global->LDS staging: per wave, 19 DMA row-slices.
    const float* gbase = logits + (size_t)n * kC * kHW + p;  // per-lane addr
#pragma unroll
    for (int c = 0; c < kC; ++c) {
        __builtin_amdgcn_global_load_lds(
            (const __attribute__((address_space(1))) void*)(gbase + (size_t)c * kHW),
            (__attribute__((address_space(3))) void*)(&sT[c][wslot]),
            4, 0, 0);
    }

    // Head loads overlap the DMA.
    bool alive = mask[gid];
    int s = alive ? seg[gid] : 0;
    unsigned tm = alive ? tmask[n * kS + s] : 0u;

    asm volatile("s_waitcnt vmcnt(0)" ::: "memory");
    __syncthreads();

    if (!tm) return;

    float sum = 0.f;
#pragma unroll
    for (int c = 0; c < kC; ++c)
        sum += __expf(sT[c][tid]);
    float inv = 1.f / sum;

    unsigned long long lowbits = (unsigned int)(~(unsigned int)p);
    unsigned long long* dst = amax + ((size_t)n * kS + s) * kC;
    unsigned bits = tm;
    while (bits) {
        int c = __ffs(bits) - 1;
        bits &= bits - 1;
        float v = __expf(sT[c][tid]) * inv;
        unsigned long long key =
            ((unsigned long long)__float_as_uint(v) << 32) | lowbits;
        atomicMax(&dst[c], key);
    }
}

// For each live (n,s,c) pair: record needed-channel bit and multiplicity.
// (R10 summation-order swap: mult lets strong emit the final loss directly.)
__global__ void need_mark_kernel(const unsigned long long* __restrict__ amax,
                                 const unsigned* __restrict__ tmask,
                                 const int* __restrict__ small_w,
                                 unsigned* __restrict__ needmask,
                                 unsigned* __restrict__ mult) {
    int gid = blockIdx.x * blockDim.x + threadIdx.x;
    if (gid >= kNSC) return;
    int n = gid / (kS * kC);
    int rem = gid - n * (kS * kC);
    int s = rem / kC;
    int c = rem - s * kC;
    if (!((tmask[n * kS + s] >> c) & 1u)) return;
    unsigned long long packed = amax[gid];
    if (packed == 0ULL) return;  // empty segment (has_pixel == false)
    unsigned pix = ~(unsigned)(packed & 0xFFFFFFFFULL);
    int sel = small_w[(size_t)n * kHW + pix];
    atomicOr(&needmask[n * kSsm + sel], 1u << c);
    atomicAdd(&mult[((size_t)n * kSsm + sel) * kC + c], 1u);
}

// Strong branch (R10, unchanged — already near its ~10 µs fetch floor):
// softmax + mult-weighted nll, block-reduced to one partial per block.
__global__ void strong_loss_kernel(const float* __restrict__ logits,
                                   const unsigned char* __restrict__ mask,
                                   const int* __restrict__ seg,
                                   const unsigned* __restrict__ needmask,
                                   const unsigned* __restrict__ mult,
                                   float* __restrict__ ploss,
                                   int* __restrict__ pnv) {
    __shared__ float sLoss[4];
    __shared__ int sNv[4];
    int gid = blockIdx.x * blockDim.x + threadIdx.x;  // exact grid
    float loss = 0.f;
    int nvv = 0;
    if (mask[gid]) {
        int n = gid >> 18;
        int p = gid & (kHW - 1);
        int ss = seg[gid];
        unsigned nm = needmask[n * kSsm + ss];
        if (nm) {
            const float* base = logits + (size_t)n * kC * kHW + p;
            float sum = 0.f;
#pragma unroll
            for (int c = 0; c < kC; ++c)
                sum += __expf(base[(size_t)c * kHW]);
            float inv = 1.f / sum;

            const unsigned* row = mult + ((size_t)n * kSsm + ss) * kC;
            unsigned bits = nm;
            while (bits) {
                int c = __ffs(bits) - 1;
                bits &= bits - 1;
                unsigned m = row[c];                            // L2-resident
                float v = __expf(base[(size_t)c * kHW]) * inv;
                loss += (float)m * (-__logf(v + kEps));
                nvv += (int)m;
            }
        }
    }
    // all threads reach here (no early returns) — block reduction
#pragma unroll
    for (int off = 32; off > 0; off >>= 1) {
        loss += __shfl_down(loss, off);
        nvv += __shfl_down(nvv, off);
    }
    int wave = threadIdx.x >> 6;
    if ((threadIdx.x & 63) == 0) {
        sLoss[wave] = loss;
        sNv[wave] = nvv;
    }
    __syncthreads();
    if (threadIdx.x == 0) {
        ploss[blockIdx.x] = sLoss[0] + sLoss[1] + sLoss[2] + sLoss[3];
        pnv[blockIdx.x]   = sNv[0] + sNv[1] + sNv[2] + sNv[3];
    }
}

// Single-block reduction of the 4096 per-block partials + final divide.
__global__ void finalize_kernel(const float* __restrict__ ploss,
                                const int* __restrict__ pnv,
                                float* __restrict__ out) {
    __shared__ float sLoss[4];
    __shared__ int sNv[4];
    float lv = 0.f;
    int nvv = 0;
    for (int i = threadIdx.x; i < kPixBlocks; i += 256) {
        lv += ploss[i];
        nvv += pnv[i];
    }
#pragma unroll
    for (int off = 32; off > 0; off >>= 1) {
        lv += __shfl_down(lv, off);
        nvv += __shfl_down(nvv, off);
    }
    int wave = threadIdx.x >> 6;
    if ((threadIdx.x & 63) == 0) {
        sLoss[wave] = lv;
        sNv[wave] = nvv;
    }
    __syncthreads();
    if (threadIdx.x == 0) {
        float tl = sLoss[0] + sLoss[1] + sLoss[2] + sLoss[3];
        int tn = sNv[0] + sNv[1] + sNv[2] + sNv[3];
        out[0] = tl / (float)(1 + tn);
    }
}

extern "C" void kernel_launch(void* const* d_in, const int* in_sizes, int n_in,
                              void* d_out, int out_size, void* d_ws, size_t ws_size,
                              hipStream_t stream) {
    const float* inputs            = (const float*)d_in[0];
    const float* inputs_weak       = (const float*)d_in[1];
    const float* targets           = (const float*)d_in[2];
    const unsigned char* spmasks      = (const unsigned char*)d_in[3];
    const unsigned char* spmasks_weak = (const unsigned char*)d_in[4];
    // d_in[5] superpixels: unused by the reference
    const int* superpixels_weak    = (const int*)d_in[6];
    const int* superpixel_smalls   = (const int*)d_in[7];
    const int* spx_smalls_weak     = (const int*)d_in[8];
    float* out = (float*)d_out;

    unsigned long long* amax = (unsigned long long*)((char*)d_ws + OFF_AMAX);
    unsigned* mult           = (unsigned*)((char*)d_ws + OFF_MULT);
    unsigned* needmask       = (unsigned*)((char*)d_ws + OFF_NM);
    unsigned* tmask          = (unsigned*)((char*)d_ws + OFF_TM);
    float* ploss             = (float*)((char*)d_ws + OFF_PL);
    int* pnv                 = (int*)((char*)d_ws + OFF_PN);

    int initThreads = (int)ZERO_CHUNKS;
    init_kernel<<<(initThreads + 255) / 256, 256, 0, stream>>>(targets, tmask,
                                                               (ulong2*)d_ws);
    weak_argmax_kernel<<<kPixBlocks, 256, 0, stream>>>(inputs_weak, spmasks_weak,
                                                       superpixels_weak, tmask, amax);
    need_mark_kernel<<<(kNSC + 255) / 256, 256, 0, stream>>>(amax, tmask,
                                                             spx_smalls_weak,
                                                             needmask, mult);
    strong_loss_kernel<<<kPixBlocks, 256, 0, stream>>>(inputs, spmasks,
                                                       superpixel_smalls,
                                                       needmask, mult, ploss, pnv);
    finalize_kernel<<<1, 256, 0, stream>>>(ploss, pnv, out);
}